// Round 20
// baseline (172.416 us; speedup 1.0000x reference)
//
#include <hip/hip_runtime.h>
#include <hip/hip_bf16.h>

// B=4, T=2048, E=768, H=12, hd=64.
// Round 20: GEMM wave = 64x128 (acc 4x8): 12 ds_read_b128 -> 32 MFMA per
// wave-iter (2.67 MFMA/read vs 2.0), 2-wave blocks (cheaper barriers).
// Same 128x128 block tile/grids, frag-tiled inputs, 3-buffer counted-vmcnt
// (vmcnt(8) per 8-load sets), XCD swizzle. attn/prepasses = round 19.

#define BB 4
#define TT 2048
#define EE 768
#define HH 12
#define HD 64
#define KK 768
#define BTE (BB*TT*EE)  // 6291456

typedef __attribute__((ext_vector_type(8))) short bf16x8;
typedef __attribute__((ext_vector_type(4))) float f32x4;
typedef __attribute__((ext_vector_type(16))) float f32x16;
typedef __attribute__((ext_vector_type(4))) int i32x4;

#define QSC 0.18033688011112042f   // 0.125 * log2(e)

#define GLOAD16(gp, lp) \
    __builtin_amdgcn_global_load_lds( \
        (const __attribute__((address_space(1))) unsigned*)(gp), \
        (__attribute__((address_space(3))) unsigned*)(lp), 16, 0, 0)

static __device__ __forceinline__ unsigned short f2bf(float f) {
    unsigned u = __builtin_bit_cast(unsigned, f);
    u += 0x7fffu + ((u >> 16) & 1u);   // RNE
    return (unsigned short)(u >> 16);
}

static __device__ __forceinline__ unsigned cvt_pk_bf16(float lo, float hi) {
    unsigned r;
    asm("v_cvt_pk_bf16_f32 %0, %1, %2" : "=v"(r) : "v"(lo), "v"(hi));
    return r;
}

// ---------------------------------------------------------------------------
// x f32 [8192][768] -> xf frag-tiled bf16. Block = one 16-row tile (24 chunks).
// ---------------------------------------------------------------------------
__global__ __launch_bounds__(256)
void convx_kernel(const float* __restrict__ x, unsigned short* __restrict__ xf) {
    const int t16 = blockIdx.x;            // 0..511
    const int tid = threadIdx.x;
    const int l = tid & 63;
    const int row = t16 * 16 + (l & 15);
    const int kbase = (l >> 4) << 3;       // 0,8,16,24
#pragma unroll
    for (int pass = 0; pass < 6; ++pass) {
        const int kb = (tid >> 6) + 4 * pass;   // 0..23
        const int k = kb * 32 + kbase;
        float4 a = *(const float4*)&x[(size_t)row * KK + k];
        float4 b = *(const float4*)&x[(size_t)row * KK + k + 4];
        ushort4 lo, hi;
        lo.x = f2bf(a.x); lo.y = f2bf(a.y); lo.z = f2bf(a.z); lo.w = f2bf(a.w);
        hi.x = f2bf(b.x); hi.y = f2bf(b.y); hi.z = f2bf(b.z); hi.w = f2bf(b.w);
        unsigned short* dst = &xf[((size_t)t16 * 24 + kb) * 512 + l * 8];
        *(ushort4*)dst = lo;
        *(ushort4*)(dst + 4) = hi;
    }
}

// ---------------------------------------------------------------------------
// W[768][N] f32 -> Wf frag-tiled bf16 ([N/16 tiles][24 chunks][lane][8]).
// ---------------------------------------------------------------------------
__global__ __launch_bounds__(256)
void transw_kernel(const float* __restrict__ W, unsigned short* __restrict__ Wf, int N) {
    __shared__ unsigned short Ts[64][72];
    const int n0 = blockIdx.x * 64;
    const int k0 = blockIdx.y * 64;
    const int tid = threadIdx.x;
    {
        const int r = tid >> 4;
        const int c4 = (tid & 15) << 2;
#pragma unroll
        for (int i = 0; i < 4; ++i) {
            const int k = r + i * 16;
            float4 w4 = *(const float4*)&W[(size_t)(k0 + k) * N + n0 + c4];
            Ts[k][c4 + 0] = f2bf(w4.x); Ts[k][c4 + 1] = f2bf(w4.y);
            Ts[k][c4 + 2] = f2bf(w4.z); Ts[k][c4 + 3] = f2bf(w4.w);
        }
    }
    __syncthreads();
#pragma unroll
    for (int i = 0; i < 2; ++i) {
        const int idx = tid + i * 256;      // 0..511
        const int sub = idx >> 6;           // 0..7
        const int l = idx & 63;
        const int n16l = sub & 3, kbl = sub >> 2;
        const int nloc = n16l * 16 + (l & 15);
        const int kloc = kbl * 32 + ((l >> 4) << 3);
        ushort4 p0, p1;
        p0.x = Ts[kloc + 0][nloc]; p0.y = Ts[kloc + 1][nloc];
        p0.z = Ts[kloc + 2][nloc]; p0.w = Ts[kloc + 3][nloc];
        p1.x = Ts[kloc + 4][nloc]; p1.y = Ts[kloc + 5][nloc];
        p1.z = Ts[kloc + 6][nloc]; p1.w = Ts[kloc + 7][nloc];
        const int n16 = (n0 >> 4) + n16l;
        const int kb  = (k0 >> 5) + kbl;
        unsigned short* dst = &Wf[((size_t)n16 * 24 + kb) * 512 + l * 8];
        *(ushort4*)dst = p0;
        *(ushort4*)(dst + 4) = p1;
    }
}

// ---------------------------------------------------------------------------
// bf16 MFMA GEMM: frag-tiled A/B, 2 waves x (64x128 acc 4x8), 3-buffer
// counted-vmcnt (8-load sets), XCD swizzle, conflict-free frag reads.
// MODE 0: 32x32-frag-order q/k/v epilogue. MODE 1: f32 row-major out.
// ---------------------------------------------------------------------------
template<int MODE>
__global__ __launch_bounds__(128)
void mfma_gemm_kernel(const unsigned short* __restrict__ Af,
                      const unsigned short* __restrict__ Bf,
                      unsigned short* __restrict__ q_ws,
                      unsigned short* __restrict__ k_ws,
                      unsigned short* __restrict__ v_ws,
                      float* __restrict__ outf) {
    __shared__ __align__(16) unsigned short As[3][8 * 512];
    __shared__ __align__(16) unsigned short Bs[3][8 * 512];

    // bijective XCD chunk swizzle (nwg % 8 == 0 for both grids used here)
    const int nwg = gridDim.x * gridDim.y;
    const int orig = blockIdx.y * gridDim.x + blockIdx.x;
    const int cpx = nwg >> 3;
    const int swz = (orig & 7) * cpx + (orig >> 3);
    const int bx = swz % gridDim.x;
    const int by = swz / gridDim.x;

    const int tid = threadIdx.x;
    const int w = tid >> 6, lane = tid & 63;   // w in {0,1}
    const int c = lane & 15, g = lane >> 4;
    const int m0 = by * 128, n0 = bx * 128;

    const unsigned short* Ap = Af + ((size_t)(m0 >> 4) * 24) * 512;
    const unsigned short* Bp = Bf + ((size_t)(n0 >> 4) * 24) * 512;

    f32x4 acc[4][8] = {};
    const int NT = KK / 32;            // 24

    // one staging set = 8 contiguous-1KB global_load_lds per wave:
    // wave w stages A-chunks [4w,4w+4) and B-chunks [4w,4w+4)
#define GSTAGE(pp, kt_) do { const int f0_ = 4 * w; \
        GLOAD16(Ap + ((size_t)(f0_ + 0) * 24 + (kt_)) * 512 + lane * 8, &As[pp][(f0_ + 0) * 512]); \
        GLOAD16(Ap + ((size_t)(f0_ + 1) * 24 + (kt_)) * 512 + lane * 8, &As[pp][(f0_ + 1) * 512]); \
        GLOAD16(Ap + ((size_t)(f0_ + 2) * 24 + (kt_)) * 512 + lane * 8, &As[pp][(f0_ + 2) * 512]); \
        GLOAD16(Ap + ((size_t)(f0_ + 3) * 24 + (kt_)) * 512 + lane * 8, &As[pp][(f0_ + 3) * 512]); \
        GLOAD16(Bp + ((size_t)(f0_ + 0) * 24 + (kt_)) * 512 + lane * 8, &Bs[pp][(f0_ + 0) * 512]); \
        GLOAD16(Bp + ((size_t)(f0_ + 1) * 24 + (kt_)) * 512 + lane * 8, &Bs[pp][(f0_ + 1) * 512]); \
        GLOAD16(Bp + ((size_t)(f0_ + 2) * 24 + (kt_)) * 512 + lane * 8, &Bs[pp][(f0_ + 2) * 512]); \
        GLOAD16(Bp + ((size_t)(f0_ + 3) * 24 + (kt_)) * 512 + lane * 8, &Bs[pp][(f0_ + 3) * 512]); \
    } while (0)

    GSTAGE(0, 0);
    GSTAGE(1, 1);

    for (int kt = 0; kt < NT; ++kt) {
        if (kt < NT - 1) asm volatile("s_waitcnt vmcnt(8)" ::: "memory");
        else             asm volatile("s_waitcnt vmcnt(0)" ::: "memory");
        __builtin_amdgcn_s_barrier();
        __builtin_amdgcn_sched_barrier(0);
        asm volatile("" ::: "memory");

        if (kt + 2 < NT) GSTAGE((kt + 2) % 3, kt + 2);

        const int p = kt % 3;
        bf16x8 af[4], bfr[8];
#pragma unroll
        for (int m = 0; m < 4; ++m)     // wave w's 64 rows: chunks 4w+m
            af[m] = *(const bf16x8*)&As[p][(w * 4 + m) * 512 + lane * 8];
#pragma unroll
        for (int n = 0; n < 8; ++n)     // all 128 cols
            bfr[n] = *(const bf16x8*)&Bs[p][n * 512 + lane * 8];
#pragma unroll
        for (int m = 0; m < 4; ++m)
#pragma unroll
            for (int n = 0; n < 8; ++n)
                acc[m][n] = __builtin_amdgcn_mfma_f32_16x16x32_bf16(af[m], bfr[n], acc[m][n], 0, 0, 0);
    }
#undef GSTAGE

    if (MODE == 0) {
        // row t = tb + m*16 + 4g + j (tb mult of 64); col = n0 + n*16 + c
        const int which = n0 / EE;
        const int hbase = (n0 % EE) / HD;
        const int bb = m0 / TT;
        const int tb = (m0 % TT) + w * 64;
        if (which < 2) {
            const float sc_ = (which == 0) ? QSC : 1.0f;
            unsigned short* dst = (which == 0) ? q_ws : k_ws;
#pragma unroll
            for (int m = 0; m < 4; ++m) {
                const int t32 = (tb >> 5) + (m >> 1);
#pragma unroll
                for (int n = 0; n < 8; ++n) {
                    const int bh = bb * HH + hbase + (n >> 2);
                    unsigned short* base = dst
                        + ((size_t)(bh * (TT / 32) + t32) * 4 + (n & 3)) * 512
                        + ((m & 1) * 16 + 4 * g + 32 * (c >> 3)) * 8 + (c & 7);
#pragma unroll
                    for (int j = 0; j < 4; ++j)
                        base[j * 8] = f2bf(acc[m][n][j] * sc_);
                }
            }
        } else {
#pragma unroll
            for (int m = 0; m < 4; ++m)
#pragma unroll
                for (int n = 0; n < 8; ++n) {
                    const int bh = bb * HH + hbase + (n >> 2);
                    const int np = n & 3;
                    unsigned short* vb = v_ws + ((size_t)(bh * (TT / 64) + (tb >> 6))) * 4096;
                    unsigned short* base = vb + ((size_t)(np >> 1) * 4 + m) * 512
                        + ((np & 1) * 16 + c + 32 * (g >> 1)) * 8 + 4 * (g & 1);
                    ushort4 pk;
                    pk.x = f2bf(acc[m][n][0]); pk.y = f2bf(acc[m][n][1]);
                    pk.z = f2bf(acc[m][n][2]); pk.w = f2bf(acc[m][n][3]);
                    *(ushort4*)base = pk;
                }
        }
    } else {
#pragma unroll
        for (int m = 0; m < 4; ++m)
#pragma unroll
            for (int n = 0; n < 8; ++n)
#pragma unroll
                for (int j = 0; j < 4; ++j)
                    outf[(size_t)(m0 + w * 64 + m * 16 + 4 * g + j) * EE
                         + n0 + n * 16 + c] = acc[m][n][j];
    }
}

// ---------------------------------------------------------------------------
// Barrier-free 32x32 swapped-QK^T flash attention (r17 core); epilogue
// writes frag-tiled attn_f (A-layout for the proj GEMM). Unchanged from r19.
// ---------------------------------------------------------------------------
__global__ __launch_bounds__(64)
void attn_kernel(const unsigned short* __restrict__ qf,
                 const unsigned short* __restrict__ kfr,
                 const unsigned short* __restrict__ vfr,
                 unsigned short* __restrict__ attn_f) {
    const int bh = blockIdx.x;
    const int j = (TT / 32 - 1) - (int)blockIdx.y;   // heavy q-tiles first
    const int b = bh / HH, h = bh % HH;
    const int lane = threadIdx.x;
    const int lq = lane & 31;
    const int hiL = lane >> 5;

    const int q0 = j * 32;
    const int qg = q0 + lq;

    const unsigned short* qbase = qf + ((size_t)(bh * (TT / 32) + j)) * 2048;
    bf16x8 qa[4];
#pragma unroll
    for (int ds = 0; ds < 4; ++ds)
        qa[ds] = *(const bf16x8*)&qbase[ds * 512 + lane * 8];

    const unsigned short* kfb = kfr + (size_t)bh * 131072;   // [t32][ds][lane][8]
    const unsigned short* vfb = vfr + (size_t)bh * 131072;   // [kv64][dt*4+ks][lane][8]

    const i32x4 onesw = {0x3F803F80, 0x3F803F80, 0x3F803F80, 0x3F803F80};
    const bf16x8 ones = __builtin_bit_cast(bf16x8, onesw);

    f32x16 o0 = {}, o1 = {}, ol = {};   // O[q=crow(r,hi)][d], l in O-layout

    const int ktiles = (j >> 1) + 1;

    for (int kt = 0; kt < ktiles; ++kt) {
        const int kv0 = kt * 64;

        bf16x8 kf[8], vf[8];
        {
            const unsigned short* kc = kfb + ((size_t)(2 * kt) * 4) * 512 + lane * 8;
#pragma unroll
            for (int ch = 0; ch < 8; ++ch)
                kf[ch] = *(const bf16x8*)&kc[ch * 512];
            const unsigned short* vc = vfb + (size_t)kt * 4096 + lane * 8;
#pragma unroll
            for (int ch = 0; ch < 8; ++ch)
                vf[ch] = *(const bf16x8*)&vc[ch * 512];
        }

        // ---- QK^T: two 32x32 S tiles ----
        f32x16 s0 = {}, s1 = {};
        __builtin_amdgcn_s_setprio(1);
#pragma unroll
        for (int ds = 0; ds < 4; ++ds) {
            s0 = __builtin_amdgcn_mfma_f32_32x32x16_bf16(kf[ds],     qa[ds], s0, 0, 0, 0);
            s1 = __builtin_amdgcn_mfma_f32_32x32x16_bf16(kf[4 + ds], qa[ds], s1, 0, 0, 0);
        }
        __builtin_amdgcn_s_setprio(0);

        if (kv0 + 63 > q0) {   // diagonal region: causal mask (in place)
#pragma unroll
            for (int r = 0; r < 16; ++r) {
                const int crow = (r & 3) + 8 * (r >> 2) + 4 * hiL;
                if (kv0 + crow > qg)      s0[r] = -INFINITY;
                if (kv0 + 32 + crow > qg) s1[r] = -INFINITY;
            }
        }

        // p = 2^s directly (log2-domain scores, |s|~3; shift-invariant;
        // exp2(-inf)=0 handles the mask)
#pragma unroll
        for (int r = 0; r < 16; ++r) s0[r] = __builtin_amdgcn_exp2f(s0[r]);
#pragma unroll
        for (int r = 0; r < 16; ++r) s1[r] = __builtin_amdgcn_exp2f(s1[r]);

        // ---- pack (cvt_pk + permlane32_swap) + PV + l (ones-MFMA) ----
        __builtin_amdgcn_s_setprio(1);
#define PACKSTEP(E0,E1,E2,E3,E4,E5,E6,E7, VK) do { \
        unsigned a0 = cvt_pk_bf16(E0, E1); \
        unsigned a1 = cvt_pk_bf16(E2, E3); \
        unsigned b0 = cvt_pk_bf16(E4, E5); \
        unsigned b1 = cvt_pk_bf16(E6, E7); \
        asm("v_permlane32_swap_b32 %0, %1" : "+v"(a0), "+v"(b0)); \
        asm("v_permlane32_swap_b32 %0, %1" : "+v"(a1), "+v"(b1)); \
        i32x4 pw; \
        pw[0] = (int)a0; pw[1] = (int)a1; pw[2] = (int)b0; pw[3] = (int)b1; \
        const bf16x8 pa = __builtin_bit_cast(bf16x8, pw); \
        o0 = __builtin_amdgcn_mfma_f32_32x32x16_bf16(pa, vf[VK],     o0, 0, 0, 0); \
        o1 = __builtin_amdgcn_mfma_f32_32x32x16_bf16(pa, vf[4 + VK], o1, 0, 0, 0); \
        ol = __builtin_amdgcn_mfma_f32_32x32x16_bf16(pa, ones,       ol, 0, 0, 0); \
    } while (0)

        PACKSTEP(s0[0], s0[1], s0[2], s0[3], s0[4], s0[5], s0[6], s0[7], 0);
        PACKSTEP(s0[8], s0[9], s0[10], s0[11], s0[12], s0[13], s0[14], s0[15], 1);
        PACKSTEP(s1[0], s1[1], s1[2], s1[3], s1[4], s1[5], s1[6], s1[7], 2);
        PACKSTEP(s1[8], s1[9], s1[10], s1[11], s1[12], s1[13], s1[14], s1[15], 3);
#undef PACKSTEP
        __builtin_amdgcn_s_setprio(0);
    }

    // epilogue: O / l -> frag-tiled attn_f
    const int rbase = b * TT + q0;     // global row base (multiple of 32)
#pragma unroll
    for (int r = 0; r < 16; ++r) {
        const int crow = (r & 3) + 8 * (r >> 2) + 4 * hiL;
        const float li = 1.f / ol[r];
        const int t16 = (rbase + crow) >> 4;
        const int lA = (crow & 15) + 16 * (lq >> 3);
        const int e  = lq & 7;
        attn_f[((size_t)t16 * 24 + (h * 2 + 0)) * 512 + lA * 8 + e] = f2bf(o0[r] * li);
        attn_f[((size_t)t16 * 24 + (h * 2 + 1)) * 512 + lA * 8 + e] = f2bf(o1[r] * li);
    }
}

extern "C" void kernel_launch(void* const* d_in, const int* in_sizes, int n_in,
                              void* d_out, int out_size, void* d_ws, size_t ws_size,
                              hipStream_t stream) {
    const float* x     = (const float*)d_in[0];
    const float* wqkv  = (const float*)d_in[1];
    const float* wproj = (const float*)d_in[2];
    float* out = (float*)d_out;

    unsigned short* ws = (unsigned short*)d_ws;
    unsigned short* q_ws    = ws;                    // 32x32 frag order (pre-scaled)
    unsigned short* k_ws    = ws + (size_t)BTE;      // frag order
    unsigned short* v_ws    = ws + 2 * (size_t)BTE;  // frag order
    unsigned short* xf      = ws + 3 * (size_t)BTE;  // frag-tiled [512][24][64][8]
    unsigned short* attn_f  = ws + 4 * (size_t)BTE;  // frag-tiled
    unsigned short* wqkv_f  = ws + 5 * (size_t)BTE;  // frag-tiled [144][24][64][8]
    unsigned short* wproj_f = wqkv_f + (size_t)2304 * 768;

    convx_kernel<<<TT * BB / 16, 256, 0, stream>>>(x, xf);
    transw_kernel<<<dim3(2304 / 64, KK / 64), 256, 0, stream>>>(wqkv, wqkv_f, 2304);
    transw_kernel<<<dim3(768 / 64, KK / 64), 256, 0, stream>>>(wproj, wproj_f, 768);

    mfma_gemm_kernel<0><<<dim3(2304 / 128, 8192 / 128), 128, 0, stream>>>(
        xf, wqkv_f, q_ws, k_ws, v_ws, nullptr);
    attn_kernel<<<dim3(BB * HH, TT / 32), 64, 0, stream>>>(q_ws, k_ws, v_ws, attn_f);
    mfma_gemm_kernel<1><<<dim3(EE / 128, 8192 / 128), 128, 0, stream>>>(
        attn_f, wproj_f, nullptr, nullptr, nullptr, out);
}

// Round 21
// 120.890 us; speedup vs baseline: 1.4262x; 1.4262x over previous
//
#include <hip/hip_runtime.h>
#include <hip/hip_bf16.h>

// B=4, T=2048, E=768, H=12, hd=64.
// Round 21: REVERT to round 19 (proven best, 124 us) + T5 setprio around
// the GEMM MFMA cluster (counted-vmcnt loop has wave role diversity:
// stagers vs MFMA-issuers -> the m218b/m224 gate condition).
// r20's 2-wave blocks regressed (occupancy 9%): 128^2/4-wave/3-blocks-CU
// is the residency sweet spot; 64x64/wave LDS-feed ceiling = 42% MfmaUtil.

#define BB 4
#define TT 2048
#define EE 768
#define HH 12
#define HD 64
#define KK 768
#define BTE (BB*TT*EE)  // 6291456

typedef __attribute__((ext_vector_type(8))) short bf16x8;
typedef __attribute__((ext_vector_type(4))) float f32x4;
typedef __attribute__((ext_vector_type(16))) float f32x16;
typedef __attribute__((ext_vector_type(4))) int i32x4;

#define QSC 0.18033688011112042f   // 0.125 * log2(e)

#define GLOAD16(gp, lp) \
    __builtin_amdgcn_global_load_lds( \
        (const __attribute__((address_space(1))) unsigned*)(gp), \
        (__attribute__((address_space(3))) unsigned*)(lp), 16, 0, 0)

static __device__ __forceinline__ unsigned short f2bf(float f) {
    unsigned u = __builtin_bit_cast(unsigned, f);
    u += 0x7fffu + ((u >> 16) & 1u);   // RNE
    return (unsigned short)(u >> 16);
}

static __device__ __forceinline__ unsigned cvt_pk_bf16(float lo, float hi) {
    unsigned r;
    asm("v_cvt_pk_bf16_f32 %0, %1, %2" : "=v"(r) : "v"(lo), "v"(hi));
    return r;
}

// ---------------------------------------------------------------------------
// x f32 [8192][768] -> xf frag-tiled bf16. Block = one 16-row tile (24 chunks).
// ---------------------------------------------------------------------------
__global__ __launch_bounds__(256)
void convx_kernel(const float* __restrict__ x, unsigned short* __restrict__ xf) {
    const int t16 = blockIdx.x;            // 0..511
    const int tid = threadIdx.x;
    const int l = tid & 63;
    const int row = t16 * 16 + (l & 15);
    const int kbase = (l >> 4) << 3;       // 0,8,16,24
#pragma unroll
    for (int pass = 0; pass < 6; ++pass) {
        const int kb = (tid >> 6) + 4 * pass;   // 0..23
        const int k = kb * 32 + kbase;
        float4 a = *(const float4*)&x[(size_t)row * KK + k];
        float4 b = *(const float4*)&x[(size_t)row * KK + k + 4];
        ushort4 lo, hi;
        lo.x = f2bf(a.x); lo.y = f2bf(a.y); lo.z = f2bf(a.z); lo.w = f2bf(a.w);
        hi.x = f2bf(b.x); hi.y = f2bf(b.y); hi.z = f2bf(b.z); hi.w = f2bf(b.w);
        unsigned short* dst = &xf[((size_t)t16 * 24 + kb) * 512 + l * 8];
        *(ushort4*)dst = lo;
        *(ushort4*)(dst + 4) = hi;
    }
}

// ---------------------------------------------------------------------------
// W[768][N] f32 -> Wf frag-tiled bf16 ([N/16 tiles][24 chunks][lane][8]).
// ---------------------------------------------------------------------------
__global__ __launch_bounds__(256)
void transw_kernel(const float* __restrict__ W, unsigned short* __restrict__ Wf, int N) {
    __shared__ unsigned short Ts[64][72];
    const int n0 = blockIdx.x * 64;
    const int k0 = blockIdx.y * 64;
    const int tid = threadIdx.x;
    {
        const int r = tid >> 4;
        const int c4 = (tid & 15) << 2;
#pragma unroll
        for (int i = 0; i < 4; ++i) {
            const int k = r + i * 16;
            float4 w4 = *(const float4*)&W[(size_t)(k0 + k) * N + n0 + c4];
            Ts[k][c4 + 0] = f2bf(w4.x); Ts[k][c4 + 1] = f2bf(w4.y);
            Ts[k][c4 + 2] = f2bf(w4.z); Ts[k][c4 + 3] = f2bf(w4.w);
        }
    }
    __syncthreads();
#pragma unroll
    for (int i = 0; i < 2; ++i) {
        const int idx = tid + i * 256;      // 0..511
        const int sub = idx >> 6;           // 0..7
        const int l = idx & 63;
        const int n16l = sub & 3, kbl = sub >> 2;
        const int nloc = n16l * 16 + (l & 15);
        const int kloc = kbl * 32 + ((l >> 4) << 3);
        ushort4 p0, p1;
        p0.x = Ts[kloc + 0][nloc]; p0.y = Ts[kloc + 1][nloc];
        p0.z = Ts[kloc + 2][nloc]; p0.w = Ts[kloc + 3][nloc];
        p1.x = Ts[kloc + 4][nloc]; p1.y = Ts[kloc + 5][nloc];
        p1.z = Ts[kloc + 6][nloc]; p1.w = Ts[kloc + 7][nloc];
        const int n16 = (n0 >> 4) + n16l;
        const int kb  = (k0 >> 5) + kbl;
        unsigned short* dst = &Wf[((size_t)n16 * 24 + kb) * 512 + l * 8];
        *(ushort4*)dst = p0;
        *(ushort4*)(dst + 4) = p1;
    }
}

// ---------------------------------------------------------------------------
// bf16 MFMA GEMM: frag-tiled A/B, contiguous-1KB global_load_lds staging,
// 3-buffer counted-vmcnt pipeline, XCD swizzle, conflict-free frag reads,
// T5 setprio around the MFMA cluster.
// MODE 0: 32x32-frag-order q/k/v epilogue. MODE 1: f32 row-major out.
// ---------------------------------------------------------------------------
template<int MODE>
__global__ __launch_bounds__(256)
void mfma_gemm_kernel(const unsigned short* __restrict__ Af,
                      const unsigned short* __restrict__ Bf,
                      unsigned short* __restrict__ q_ws,
                      unsigned short* __restrict__ k_ws,
                      unsigned short* __restrict__ v_ws,
                      float* __restrict__ outf) {
    __shared__ __align__(16) unsigned short As[3][8 * 512];
    __shared__ __align__(16) unsigned short Bs[3][8 * 512];

    // bijective XCD chunk swizzle (nwg % 8 == 0 for both grids used here)
    const int nwg = gridDim.x * gridDim.y;
    const int orig = blockIdx.y * gridDim.x + blockIdx.x;
    const int cpx = nwg >> 3;
    const int swz = (orig & 7) * cpx + (orig >> 3);
    const int bx = swz % gridDim.x;
    const int by = swz / gridDim.x;

    const int tid = threadIdx.x;
    const int w = tid >> 6, lane = tid & 63;
    const int c = lane & 15, g = lane >> 4;
    const int wr = w >> 1, wc = w & 1;
    const int m0 = by * 128, n0 = bx * 128;

    const unsigned short* Ap = Af + ((size_t)(m0 >> 4) * 24) * 512;
    const unsigned short* Bp = Bf + ((size_t)(n0 >> 4) * 24) * 512;

    f32x4 acc[4][4] = {};
    const int NT = KK / 32;            // 24

    // one staging set = 4 contiguous-1KB global_load_lds per wave
#define GSTAGE(pp, kt_) do { const int f0_ = 2 * w; \
        GLOAD16(Ap + ((size_t)(f0_    ) * 24 + (kt_)) * 512 + lane * 8, &As[pp][(f0_    ) * 512]); \
        GLOAD16(Ap + ((size_t)(f0_ + 1) * 24 + (kt_)) * 512 + lane * 8, &As[pp][(f0_ + 1) * 512]); \
        GLOAD16(Bp + ((size_t)(f0_    ) * 24 + (kt_)) * 512 + lane * 8, &Bs[pp][(f0_    ) * 512]); \
        GLOAD16(Bp + ((size_t)(f0_ + 1) * 24 + (kt_)) * 512 + lane * 8, &Bs[pp][(f0_ + 1) * 512]); \
    } while (0)

    GSTAGE(0, 0);
    GSTAGE(1, 1);

    for (int kt = 0; kt < NT; ++kt) {
        if (kt < NT - 1) asm volatile("s_waitcnt vmcnt(4)" ::: "memory");
        else             asm volatile("s_waitcnt vmcnt(0)" ::: "memory");
        __builtin_amdgcn_s_barrier();
        __builtin_amdgcn_sched_barrier(0);
        asm volatile("" ::: "memory");

        if (kt + 2 < NT) GSTAGE((kt + 2) % 3, kt + 2);

        const int p = kt % 3;
        bf16x8 af[4], bfr[4];
#pragma unroll
        for (int m = 0; m < 4; ++m)     // dense lane-linear: conflict-free
            af[m] = *(const bf16x8*)&As[p][(wr * 4 + m) * 512 + lane * 8];
#pragma unroll
        for (int n = 0; n < 4; ++n)
            bfr[n] = *(const bf16x8*)&Bs[p][(wc * 4 + n) * 512 + lane * 8];
        __builtin_amdgcn_s_setprio(1);
#pragma unroll
        for (int m = 0; m < 4; ++m)
#pragma unroll
            for (int n = 0; n < 4; ++n)
                acc[m][n] = __builtin_amdgcn_mfma_f32_16x16x32_bf16(af[m], bfr[n], acc[m][n], 0, 0, 0);
        __builtin_amdgcn_s_setprio(0);
    }
#undef GSTAGE

    if (MODE == 0) {
        const int which = n0 / EE;
        const int hh = (n0 % EE) / HD + wc;
        const int bb = m0 / TT;
        const int tb = (m0 % TT) + wr * 64;
        const int bh = bb * HH + hh;
        if (which < 2) {
            const float sc_ = (which == 0) ? QSC : 1.0f;
            unsigned short* dst = (which == 0) ? q_ws : k_ws;
#pragma unroll
            for (int m = 0; m < 4; ++m) {
                const int t32 = (tb >> 5) + (m >> 1);
#pragma unroll
                for (int n = 0; n < 4; ++n) {
                    unsigned short* base = dst
                        + ((size_t)(bh * (TT / 32) + t32) * 4 + n) * 512
                        + ((m & 1) * 16 + 4 * g + 32 * (c >> 3)) * 8 + (c & 7);
#pragma unroll
                    for (int j = 0; j < 4; ++j)
                        base[j * 8] = f2bf(acc[m][n][j] * sc_);
                }
            }
        } else {
            unsigned short* vb = v_ws + ((size_t)(bh * (TT / 64) + (tb >> 6))) * 4096;
#pragma unroll
            for (int m = 0; m < 4; ++m)
#pragma unroll
                for (int n = 0; n < 4; ++n) {
                    unsigned short* base = vb + ((size_t)(n >> 1) * 4 + m) * 512
                        + ((n & 1) * 16 + c + 32 * (g >> 1)) * 8 + 4 * (g & 1);
                    ushort4 pk;
                    pk.x = f2bf(acc[m][n][0]); pk.y = f2bf(acc[m][n][1]);
                    pk.z = f2bf(acc[m][n][2]); pk.w = f2bf(acc[m][n][3]);
                    *(ushort4*)base = pk;
                }
        }
    } else {
#pragma unroll
        for (int m = 0; m < 4; ++m)
#pragma unroll
            for (int n = 0; n < 4; ++n)
#pragma unroll
                for (int j = 0; j < 4; ++j)
                    outf[(size_t)(m0 + wr * 64 + m * 16 + 4 * g + j) * EE
                         + n0 + wc * 64 + n * 16 + c] = acc[m][n][j];
    }
}

// ---------------------------------------------------------------------------
// Barrier-free 32x32 swapped-QK^T flash attention (r17 core); epilogue
// writes frag-tiled attn_f (A-layout for the proj GEMM).
// ---------------------------------------------------------------------------
__global__ __launch_bounds__(64)
void attn_kernel(const unsigned short* __restrict__ qf,
                 const unsigned short* __restrict__ kfr,
                 const unsigned short* __restrict__ vfr,
                 unsigned short* __restrict__ attn_f) {
    const int bh = blockIdx.x;
    const int j = (TT / 32 - 1) - (int)blockIdx.y;   // heavy q-tiles first
    const int b = bh / HH, h = bh % HH;
    const int lane = threadIdx.x;
    const int lq = lane & 31;
    const int hiL = lane >> 5;

    const int q0 = j * 32;
    const int qg = q0 + lq;

    const unsigned short* qbase = qf + ((size_t)(bh * (TT / 32) + j)) * 2048;
    bf16x8 qa[4];
#pragma unroll
    for (int ds = 0; ds < 4; ++ds)
        qa[ds] = *(const bf16x8*)&qbase[ds * 512 + lane * 8];

    const unsigned short* kfb = kfr + (size_t)bh * 131072;   // [t32][ds][lane][8]
    const unsigned short* vfb = vfr + (size_t)bh * 131072;   // [kv64][dt*4+ks][lane][8]

    const i32x4 onesw = {0x3F803F80, 0x3F803F80, 0x3F803F80, 0x3F803F80};
    const bf16x8 ones = __builtin_bit_cast(bf16x8, onesw);

    f32x16 o0 = {}, o1 = {}, ol = {};   // O[q=crow(r,hi)][d], l in O-layout

    const int ktiles = (j >> 1) + 1;

    for (int kt = 0; kt < ktiles; ++kt) {
        const int kv0 = kt * 64;

        bf16x8 kf[8], vf[8];
        {
            const unsigned short* kc = kfb + ((size_t)(2 * kt) * 4) * 512 + lane * 8;
#pragma unroll
            for (int ch = 0; ch < 8; ++ch)
                kf[ch] = *(const bf16x8*)&kc[ch * 512];
            const unsigned short* vc = vfb + (size_t)kt * 4096 + lane * 8;
#pragma unroll
            for (int ch = 0; ch < 8; ++ch)
                vf[ch] = *(const bf16x8*)&vc[ch * 512];
        }

        // ---- QK^T: two 32x32 S tiles ----
        f32x16 s0 = {}, s1 = {};
        __builtin_amdgcn_s_setprio(1);
#pragma unroll
        for (int ds = 0; ds < 4; ++ds) {
            s0 = __builtin_amdgcn_mfma_f32_32x32x16_bf16(kf[ds],     qa[ds], s0, 0, 0, 0);
            s1 = __builtin_amdgcn_mfma_f32_32x32x16_bf16(kf[4 + ds], qa[ds], s1, 0, 0, 0);
        }
        __builtin_amdgcn_s_setprio(0);

        if (kv0 + 63 > q0) {   // diagonal region: causal mask (in place)
#pragma unroll
            for (int r = 0; r < 16; ++r) {
                const int crow = (r & 3) + 8 * (r >> 2) + 4 * hiL;
                if (kv0 + crow > qg)      s0[r] = -INFINITY;
                if (kv0 + 32 + crow > qg) s1[r] = -INFINITY;
            }
        }

        // p = 2^s directly (log2-domain scores, |s|~3; shift-invariant;
        // exp2(-inf)=0 handles the mask)
#pragma unroll
        for (int r = 0; r < 16; ++r) s0[r] = __builtin_amdgcn_exp2f(s0[r]);
#pragma unroll
        for (int r = 0; r < 16; ++r) s1[r] = __builtin_amdgcn_exp2f(s1[r]);

        // ---- pack (cvt_pk + permlane32_swap) + PV + l (ones-MFMA) ----
        __builtin_amdgcn_s_setprio(1);
#define PACKSTEP(E0,E1,E2,E3,E4,E5,E6,E7, VK) do { \
        unsigned a0 = cvt_pk_bf16(E0, E1); \
        unsigned a1 = cvt_pk_bf16(E2, E3); \
        unsigned b0 = cvt_pk_bf16(E4, E5); \
        unsigned b1 = cvt_pk_bf16(E6, E7); \
        asm("v_permlane32_swap_b32 %0, %1" : "+v"(a0), "+v"(b0)); \
        asm("v_permlane32_swap_b32 %0, %1" : "+v"(a1), "+v"(b1)); \
        i32x4 pw; \
        pw[0] = (int)a0; pw[1] = (int)a1; pw[2] = (int)b0; pw[3] = (int)b1; \
        const bf16x8 pa = __builtin_bit_cast(bf16x8, pw); \
        o0 = __builtin_amdgcn_mfma_f32_32x32x16_bf16(pa, vf[VK],     o0, 0, 0, 0); \
        o1 = __builtin_amdgcn_mfma_f32_32x32x16_bf16(pa, vf[4 + VK], o1, 0, 0, 0); \
        ol = __builtin_amdgcn_mfma_f32_32x32x16_bf16(pa, ones,       ol, 0, 0, 0); \
    } while (0)

        PACKSTEP(s0[0], s0[1], s0[2], s0[3], s0[4], s0[5], s0[6], s0[7], 0);
        PACKSTEP(s0[8], s0[9], s0[10], s0[11], s0[12], s0[13], s0[14], s0[15], 1);
        PACKSTEP(s1[0], s1[1], s1[2], s1[3], s1[4], s1[5], s1[6], s1[7], 2);
        PACKSTEP(s1[8], s1[9], s1[10], s1[11], s1[12], s1[13], s1[14], s1[15], 3);
#undef PACKSTEP
        __builtin_amdgcn_s_setprio(0);
    }

    // epilogue: O / l -> frag-tiled attn_f
    const int rbase = b * TT + q0;     // global row base (multiple of 32)
#pragma unroll
    for (int r = 0; r < 16; ++r) {
        const int crow = (r & 3) + 8 * (r >> 2) + 4 * hiL;
        const float li = 1.f / ol[r];
        const int t16 = (rbase + crow) >> 4;
        const int lA = (crow & 15) + 16 * (lq >> 3);
        const int e  = lq & 7;
        attn_f[((size_t)t16 * 24 + (h * 2 + 0)) * 512 + lA * 8 + e] = f2bf(o0[r] * li);
        attn_f[((size_t)t16 * 24 + (h * 2 + 1)) * 512 + lA * 8 + e] = f2bf(o1[r] * li);
    }
}

extern "C" void kernel_launch(void* const* d_in, const int* in_sizes, int n_in,
                              void* d_out, int out_size, void* d_ws, size_t ws_size,
                              hipStream_t stream) {
    const float* x     = (const float*)d_in[0];
    const float* wqkv  = (const float*)d_in[1];
    const float* wproj = (const float*)d_in[2];
    float* out = (float*)d_out;

    unsigned short* ws = (unsigned short*)d_ws;
    unsigned short* q_ws    = ws;                    // 32x32 frag order (pre-scaled)
    unsigned short* k_ws    = ws + (size_t)BTE;      // frag order
    unsigned short* v_ws    = ws + 2 * (size_t)BTE;  // frag order
    unsigned short* xf      = ws + 3 * (size_t)BTE;  // frag-tiled [512][24][64][8]
    unsigned short* attn_f  = ws + 4 * (size_t)BTE;  // frag-tiled
    unsigned short* wqkv_f  = ws + 5 * (size_t)BTE;  // frag-tiled [144][24][64][8]
    unsigned short* wproj_f = wqkv_f + (size_t)2304 * 768;

    convx_kernel<<<TT * BB / 16, 256, 0, stream>>>(x, xf);
    transw_kernel<<<dim3(2304 / 64, KK / 64), 256, 0, stream>>>(wqkv, wqkv_f, 2304);
    transw_kernel<<<dim3(768 / 64, KK / 64), 256, 0, stream>>>(wproj, wproj_f, 768);

    mfma_gemm_kernel<0><<<dim3(2304 / 128, 8192 / 128), 256, 0, stream>>>(
        xf, wqkv_f, q_ws, k_ws, v_ws, nullptr);
    attn_kernel<<<dim3(BB * HH, TT / 32), 64, 0, stream>>>(q_ws, k_ws, v_ws, attn_f);
    mfma_gemm_kernel<1><<<dim3(EE / 128, 8192 / 128), 256, 0, stream>>>(
        attn_f, wproj_f, nullptr, nullptr, nullptr, out);
}